// Round 4
// baseline (3562.979 us; speedup 1.0000x reference)
//
#include <hip/hip_runtime.h>
#include <hip/hip_bf16.h>
#include <math.h>

#define BB   2048
#define LL   60
#define DD   80
#define HH   8
#define HDD  10
#define NLNUM 3
#define NLOC 1187
#define DFF  160
#define IN_DIM 138
#define RELN 119
#define SCS  68   // sc row stride (floats): 68 mod 32 = 4 -> rows spread banks

// acc[base..base+3] += S * W.{x,y,z,w}  (params uppercase: member names are
// lowercase and must not be macro-substituted)
#define ACC4(A, base, S, W)                                                  \
  { (A)[(base)] += (S) * (W).x; (A)[(base) + 1] += (S) * (W).y;              \
    (A)[(base) + 2] += (S) * (W).z; (A)[(base) + 3] += (S) * (W).w; }

// Opaque zero in a VGPR: defeats uniformity analysis so weight loads stay
// VMEM (deep, VGPR-budgeted pipelining) instead of s_load (SGPR-limited).
#define OPAQUE_ZERO(vz) asm volatile("v_mov_b32 %0, 0" : "=v"(vz))

// Branchless gelu: erf via Abramowitz-Stegun 7.1.26 (|err| <= 1.5e-7).
__device__ __forceinline__ float gelu_f(float a) {
  float x = fabsf(a) * 0.70710678118654752f;
  float t = 1.0f / (1.0f + 0.3275911f * x);
  float y = t * (0.254829592f + t * (-0.284496736f + t * (1.421413741f +
            t * (-1.453152027f + t * 1.061405429f))));
  float e = 1.0f - y * __expf(-x * x);           // erf(|x|)
  float erf_s = copysignf(e, a);
  return 0.5f * a * (1.0f + erf_s);
}

// ---------------------------------------------------------------------------
// K0: pre-transpose rel_emb [l][p:119][d:10] -> relTg [l][d:10][p:120]
// ---------------------------------------------------------------------------
__global__ __launch_bounds__(256) void k_rprep(
    const float* __restrict__ rel_emb, float* __restrict__ relTg) {
  int idx = blockIdx.x * 256 + threadIdx.x;   // 3*10*120 = 3600
  if (idx >= 3600) return;
  int p = idx % 120;
  int d = (idx / 120) % 10;
  int l = idx / 1200;
  float v = 0.0f;
  if (p < RELN) v = rel_emb[l * RELN * HDD + p * HDD + d];
  relTg[idx] = v;
}

// ---------------------------------------------------------------------------
// K1 v5: embed + inproj + LN — token per lane, WAVE-PAIR column split.
// Wave pair (pr) shares 64 tokens; wave parity q owns cols [40q,40q+40).
// Weight addresses wave-uniform; forced VMEM via opaque zero. LN sums
// exchanged via tiny LDS. 128 tokens/block, grid=960, 3840 waves.
// ---------------------------------------------------------------------------
__global__ __launch_bounds__(256, 4) void k_embed(
    const int* __restrict__ loc_seq, const int* __restrict__ user_seq,
    const int* __restrict__ wk_seq, const int* __restrict__ sm_seq,
    const int* __restrict__ dur_seq, const int* __restrict__ diff_seq,
    const float* __restrict__ loc_table, const float* __restrict__ user_table,
    const float* __restrict__ wk_table, const float* __restrict__ hr_table,
    const float* __restrict__ in_w, const float* __restrict__ in_b,
    const float* __restrict__ in_g, const float* __restrict__ in_be,
    const float* __restrict__ pos_emb, float* __restrict__ x) {
  int tid = threadIdx.x;
  int lane = tid & 63, wid = tid >> 6;
  int pr = wid >> 1, q = wid & 1;
  int g = blockIdx.x * 128 + pr * 64 + lane;  // token id
  int cb4 = q * 10;                           // col offset (float4)
  int b = g / LL, t = g - b * LL;
  int loc = loc_seq[g];
  int usr = user_seq[b * LL];
  int wk  = wk_seq[g];
  int hr  = min(max(sm_seq[g] / 60, 0), 23);
  int vz; OPAQUE_ZERO(vz);
  const float4* w4 = (const float4*)in_w + vz; // row stride 20 f4

  float acc[40];
  {
    const float4* bb4 = (const float4*)in_b;
    #pragma unroll
    for (int c4 = 0; c4 < 10; c4++) {
      float4 v = bb4[cb4 + c4];
      acc[c4 * 4] = v.x; acc[c4 * 4 + 1] = v.y;
      acc[c4 * 4 + 2] = v.z; acc[c4 * 4 + 3] = v.w;
    }
  }

  // rows 0..79: loc embedding
  const float4* le4 = (const float4*)(loc_table + (size_t)loc * DD);
  #pragma unroll 4
  for (int iq = 0; iq < 20; iq++) {
    float4 xv = le4[iq];
    const float* xp = (const float*)&xv;
    #pragma unroll
    for (int dk = 0; dk < 4; dk++) {
      float s = xp[dk];
      #pragma unroll
      for (int c4 = 0; c4 < 10; c4++) {
        float4 wv = w4[(iq * 4 + dk) * 20 + cb4 + c4];
        ACC4(acc, c4 * 4, s, wv)
      }
    }
  }
  // rows 80..103: user embedding
  const float4* ue4 = (const float4*)(user_table + usr * 24);
  #pragma unroll
  for (int iq = 0; iq < 6; iq++) {
    float4 xv = ue4[iq];
    const float* xp = (const float*)&xv;
    #pragma unroll
    for (int dk = 0; dk < 4; dk++) {
      float s = xp[dk];
      #pragma unroll
      for (int c4 = 0; c4 < 10; c4++) {
        float4 wv = w4[(80 + iq * 4 + dk) * 20 + cb4 + c4];
        ACC4(acc, c4 * 4, s, wv)
      }
    }
  }
  // rows 104..119: weekday embedding
  const float4* we4 = (const float4*)(wk_table + wk * 16);
  #pragma unroll
  for (int iq = 0; iq < 4; iq++) {
    float4 xv = we4[iq];
    const float* xp = (const float*)&xv;
    #pragma unroll
    for (int dk = 0; dk < 4; dk++) {
      float s = xp[dk];
      #pragma unroll
      for (int c4 = 0; c4 < 10; c4++) {
        float4 wv = w4[(104 + iq * 4 + dk) * 20 + cb4 + c4];
        ACC4(acc, c4 * 4, s, wv)
      }
    }
  }
  // rows 120..135: hour embedding
  const float4* he4 = (const float4*)(hr_table + hr * 16);
  #pragma unroll
  for (int iq = 0; iq < 4; iq++) {
    float4 xv = he4[iq];
    const float* xp = (const float*)&xv;
    #pragma unroll
    for (int dk = 0; dk < 4; dk++) {
      float s = xp[dk];
      #pragma unroll
      for (int c4 = 0; c4 < 10; c4++) {
        float4 wv = w4[(120 + iq * 4 + dk) * 20 + cb4 + c4];
        ACC4(acc, c4 * 4, s, wv)
      }
    }
  }
  // rows 136..137: continuous features
  {
    float xd = (float)diff_seq[g] * 0.1f;
    float xu = (float)dur_seq[g] * (1.0f / 300.0f);
    #pragma unroll
    for (int c4 = 0; c4 < 10; c4++) {
      float4 wa = w4[136 * 20 + cb4 + c4];
      float4 wb = w4[137 * 20 + cb4 + c4];
      acc[c4 * 4]     += xd * wa.x + xu * wb.x;
      acc[c4 * 4 + 1] += xd * wa.y + xu * wb.y;
      acc[c4 * 4 + 2] += xd * wa.z + xu * wb.z;
      acc[c4 * 4 + 3] += xd * wa.w + xu * wb.w;
    }
  }

  // LN over full row: wave-pair combined sums via LDS
  float s1 = 0.0f, s2 = 0.0f;
  #pragma unroll
  for (int c = 0; c < 40; c++) { s1 += acc[c]; s2 += acc[c] * acc[c]; }
  __shared__ float ssum[2][2][2][64];
  ssum[pr][q][0][lane] = s1; ssum[pr][q][1][lane] = s2;
  __syncthreads();
  s1 += ssum[pr][q ^ 1][0][lane];
  s2 += ssum[pr][q ^ 1][1][lane];
  float m = s1 * 0.0125f;
  float var = fmaxf(s2 * 0.0125f - m * m, 0.0f);
  float r = rsqrtf(var + 1e-5f);

  const float4* g4  = (const float4*)in_g;
  const float4* be4 = (const float4*)in_be;
  const float4* pe4 = (const float4*)(pos_emb + t * DD);
  float4* xo4 = (float4*)(x + (size_t)g * DD);
  #pragma unroll
  for (int c4 = 0; c4 < 10; c4++) {
    float4 gv = g4[cb4 + c4], bv = be4[cb4 + c4], pv = pe4[cb4 + c4];
    float4 ov;
    ov.x = (acc[c4 * 4]     - m) * r * gv.x + bv.x + pv.x;
    ov.y = (acc[c4 * 4 + 1] - m) * r * gv.y + bv.y + pv.y;
    ov.z = (acc[c4 * 4 + 2] - m) * r * gv.z + bv.z + pv.z;
    ov.w = (acc[c4 * 4 + 3] - m) * r * gv.w + bv.w + pv.w;
    xo4[cb4 + c4] = ov;
  }
}

// ---------------------------------------------------------------------------
// K2a (v4): qkv GEMM — one token per lane, zero LDS, pass-split across
// blocks (uniform weight addresses -> scalar loads; 24 waves/CU).
// ---------------------------------------------------------------------------
__global__ __launch_bounds__(256) void k_qkv(
    const float* __restrict__ x, const float* __restrict__ qkv_w,
    float* __restrict__ qkvo) {
  int tid = threadIdx.x;
  int pass = blockIdx.x % 3;                 // col chunk c0 = pass*80
  int b = (blockIdx.x / 3) * 4 + (tid >> 6);
  int t = tid & 63;
  int tt = min(t, 59);                       // lanes 60..63 compute, don't store
  const float4* xr4 = (const float4*)(x + ((size_t)b * LL + tt) * DD);
  const float4* w4  = (const float4*)qkv_w;  // row stride 240 fl = 60 f4
  float* ob = qkvo + (size_t)b * 14400 + t;

  int c0 = pass * 80, cq0 = pass * 20;
  float acc[DD];
  #pragma unroll
  for (int c = 0; c < DD; c++) acc[c] = 0.0f;
  for (int iq = 0; iq < 20; iq++) {
    float4 xv = xr4[iq];
    const float* xp = (const float*)&xv;
    #pragma unroll
    for (int dk = 0; dk < 4; dk++) {
      float s = xp[dk];
      #pragma unroll
      for (int c4 = 0; c4 < 20; c4++) {
        float4 wv = w4[(iq * 4 + dk) * 60 + cq0 + c4];
        ACC4(acc, c4 * 4, s, wv)
      }
    }
  }
  if (t < 60) {
    #pragma unroll
    for (int c = 0; c < DD; c++) ob[(size_t)(c0 + c) * 60] = acc[c];
  }
}

// ---------------------------------------------------------------------------
// K2b: attention per (b,h), 256 threads; relT staged via coalesced relTg.
// (unchanged)
// ---------------------------------------------------------------------------
__global__ __launch_bounds__(256) void k_attn(
    const float* __restrict__ qkvo, const int* __restrict__ loc_seq,
    const float* __restrict__ relTg,   // layer slice [10][120]
    float* __restrict__ o) {
  int bh = blockIdx.x;
  int b = bh >> 3, h = bh & 7;
  int tid = threadIdx.x;

  __shared__ __align__(16) float qs[HDD * 60];
  __shared__ __align__(16) float ks[HDD * 60];
  __shared__ __align__(16) float vs[HDD * 60];
  __shared__ __align__(16) float relT[HDD * 120];
  __shared__ __align__(16) float sc[60 * SCS];
  __shared__ __align__(16) float rsum[64];
  __shared__ float msk[60];

  const float4* src = (const float4*)(qkvo + (size_t)b * 14400);
  float4* q4 = (float4*)qs; float4* k4 = (float4*)ks; float4* v4 = (float4*)vs;
  for (int i = tid; i < 150; i += 256) {
    q4[i] = src[h * 150 + i];
    k4[i] = src[1200 + h * 150 + i];
    v4[i] = src[2400 + h * 150 + i];
  }
  const float4* rg4 = (const float4*)relTg;
  float4* relT4 = (float4*)relT;
  for (int i = tid; i < 300; i += 256) relT4[i] = rg4[i];
  if (tid < 60) msk[tid] = (loc_seq[b * LL + tid] == 0) ? 1.0f : 0.0f;
  __syncthreads();

  if (tid < 225) {
    int ig = tid / 15, jg = tid % 15;
    int i0 = ig * 4, j0 = jg * 4;
    int w0 = j0 - i0 + 56;
    float acc[4][4] = {};
    #pragma unroll
    for (int d = 0; d < 10; d++) {
      float4 qv = *(const float4*)(qs + d * 60 + i0);
      float4 kv = *(const float4*)(ks + d * 60 + j0);
      float4 rA = *(const float4*)(relT + d * 120 + w0);
      float4 rB = *(const float4*)(relT + d * 120 + w0 + 4);
      float rr[8] = {rA.x, rA.y, rA.z, rA.w, rB.x, rB.y, rB.z, rB.w};
      const float* qp = (const float*)&qv;
      const float* kp = (const float*)&kv;
      #pragma unroll
      for (int di = 0; di < 4; di++)
        #pragma unroll
        for (int dj = 0; dj < 4; dj++)
          acc[di][dj] += qp[di] * (kp[dj] + rr[dj - di + 3]);
    }
    const float scale = 0.31622776601683794f;
    #pragma unroll
    for (int di = 0; di < 4; di++) {
      #pragma unroll
      for (int dj = 0; dj < 4; dj++) {
        float v = acc[di][dj] * scale;
        if (msk[j0 + dj] != 0.0f) v = -1e30f;
        acc[di][dj] = v;
      }
      *(float4*)(sc + (i0 + di) * SCS + j0) =
          make_float4(acc[di][0], acc[di][1], acc[di][2], acc[di][3]);
    }
  }
  __syncthreads();

  if (tid < 60) {
    float* row = sc + tid * SCS;
    int c = (tid >> 3) & 7;
    float m0 = -3.0e38f, m1 = -3.0e38f, m2 = -3.0e38f, m3 = -3.0e38f;
    #pragma unroll
    for (int s = 0; s < 15; s++) {
      int k = c + s; if (k >= 15) k -= 15;
      float4 v = *(const float4*)(row + 4 * k);
      m0 = fmaxf(m0, v.x); m1 = fmaxf(m1, v.y);
      m2 = fmaxf(m2, v.z); m3 = fmaxf(m3, v.w);
    }
    float m = fmaxf(fmaxf(m0, m1), fmaxf(m2, m3));
    float s0 = 0.0f, s1 = 0.0f, s2 = 0.0f, s3 = 0.0f;
    #pragma unroll
    for (int s = 0; s < 15; s++) {
      int k = c + s; if (k >= 15) k -= 15;
      float4 v = *(float4*)(row + 4 * k);
      v.x = __expf(v.x - m); v.y = __expf(v.y - m);
      v.z = __expf(v.z - m); v.w = __expf(v.w - m);
      *(float4*)(row + 4 * k) = v;
      s0 += v.x; s1 += v.y; s2 += v.z; s3 += v.w;
    }
    rsum[tid] = 1.0f / (s0 + s1 + s2 + s3);
  }
  __syncthreads();

  if (tid < 150) {
    int ig = tid / 10, d = tid % 10;
    float acc[4] = {0, 0, 0, 0};
    #pragma unroll 5
    for (int jq = 0; jq < 15; jq++) {
      float4 vv = *(const float4*)(vs + d * 60 + jq * 4);
      #pragma unroll
      for (int di = 0; di < 4; di++) {
        float4 av = *(const float4*)(sc + (ig + 15 * di) * SCS + jq * 4);
        acc[di] += av.x * vv.x + av.y * vv.y + av.z * vv.z + av.w * vv.w;
      }
    }
    #pragma unroll
    for (int di = 0; di < 4; di++) {
      float r = rsum[ig + 15 * di];
      o[((size_t)b * 60 + ig + 15 * di) * 80 + h * 10 + d] = acc[di] * r;
    }
  }
}

// ---------------------------------------------------------------------------
// K3a v5: proj + residual + LN1 -> y. Token per lane, WAVE-PAIR column split
// (q owns cols [40q,40q+40)); uniform weight addrs forced to VMEM.
// 128 tokens/block, grid=960.
// ---------------------------------------------------------------------------
__global__ __launch_bounds__(256, 4) void k_proj(
    const float* __restrict__ o, const float* __restrict__ proj_w,
    const float* __restrict__ proj_b, const float* __restrict__ g1,
    const float* __restrict__ be1, const float* __restrict__ x,
    float* __restrict__ y) {
  int tid = threadIdx.x;
  int lane = tid & 63, wid = tid >> 6;
  int pr = wid >> 1, q = wid & 1;
  int g = blockIdx.x * 128 + pr * 64 + lane;  // token id
  int cb4 = q * 10;
  int vz; OPAQUE_ZERO(vz);
  const float4* or4 = (const float4*)(o + (size_t)g * DD);
  const float4* xr4 = (const float4*)(x + (size_t)g * DD);
  const float4* pw4 = (const float4*)proj_w + vz;  // row stride 20 f4

  float acc[40];
  #pragma unroll
  for (int c = 0; c < 40; c++) acc[c] = 0.0f;
  #pragma unroll 4
  for (int iq = 0; iq < 20; iq++) {
    float4 xv = or4[iq];
    const float* xp = (const float*)&xv;
    #pragma unroll
    for (int dk = 0; dk < 4; dk++) {
      float s = xp[dk];
      #pragma unroll
      for (int c4 = 0; c4 < 10; c4++) {
        float4 wv = pw4[(iq * 4 + dk) * 20 + cb4 + c4];
        ACC4(acc, c4 * 4, s, wv)
      }
    }
  }
  float s1 = 0.0f, s2 = 0.0f;
  #pragma unroll
  for (int c4 = 0; c4 < 10; c4++) {
    float4 pb = ((const float4*)proj_b)[cb4 + c4];
    float4 xv = xr4[cb4 + c4];                 // residual (pre-LN x)
    float v0 = acc[c4 * 4]     + pb.x + xv.x;
    float v1 = acc[c4 * 4 + 1] + pb.y + xv.y;
    float v2 = acc[c4 * 4 + 2] + pb.z + xv.z;
    float v3 = acc[c4 * 4 + 3] + pb.w + xv.w;
    acc[c4 * 4] = v0; acc[c4 * 4 + 1] = v1;
    acc[c4 * 4 + 2] = v2; acc[c4 * 4 + 3] = v3;
    s1 += v0 + v1 + v2 + v3;
    s2 += v0 * v0 + v1 * v1 + v2 * v2 + v3 * v3;
  }
  __shared__ float ssum[2][2][2][64];
  ssum[pr][q][0][lane] = s1; ssum[pr][q][1][lane] = s2;
  __syncthreads();
  s1 += ssum[pr][q ^ 1][0][lane];
  s2 += ssum[pr][q ^ 1][1][lane];
  float m = s1 * 0.0125f;
  float var = fmaxf(s2 * 0.0125f - m * m, 0.0f);
  float r = rsqrtf(var + 1e-5f);
  float4* yo4 = (float4*)(y + (size_t)g * DD);
  #pragma unroll
  for (int c4 = 0; c4 < 10; c4++) {
    float4 gv = ((const float4*)g1)[cb4 + c4];
    float4 bv = ((const float4*)be1)[cb4 + c4];
    float4 ov;
    ov.x = (acc[c4 * 4]     - m) * r * gv.x + bv.x;
    ov.y = (acc[c4 * 4 + 1] - m) * r * gv.y + bv.y;
    ov.z = (acc[c4 * 4 + 2] - m) * r * gv.z + bv.z;
    ov.w = (acc[c4 * 4 + 3] - m) * r * gv.w + bv.w;
    yo4[cb4 + c4] = ov;
  }
}

// ---------------------------------------------------------------------------
// K3b v5: FFN + LN2 -> x. Token per lane; WAVE-PAIR splits the HIDDEN dim
// (q owns hidden [80q,80q+80)); each wave holds full y and a partial out[80];
// partials combined via conflict-free column-major LDS (40 KB) + 1 barrier;
// odd wave finishes LN2. grid=960, 128 tokens/block.
// ---------------------------------------------------------------------------
__global__ __launch_bounds__(256, 2) void k_ffn(
    const float* __restrict__ yg, const float* __restrict__ w1,
    const float* __restrict__ b1, const float* __restrict__ w2,
    const float* __restrict__ b2, const float* __restrict__ g2,
    const float* __restrict__ be2, float* __restrict__ x) {
  int tid = threadIdx.x;
  int lane = tid & 63, wid = tid >> 6;
  int pr = wid >> 1, q = wid & 1;
  int g = blockIdx.x * 128 + pr * 64 + lane;  // token id
  int vz; OPAQUE_ZERO(vz);
  const float4* yr4 = (const float4*)(yg + (size_t)g * DD);
  const float4* w14 = (const float4*)w1 + vz;  // row stride 40 f4
  const float4* w24 = (const float4*)w2 + vz;  // row stride 20 f4

  float y[DD];
  #pragma unroll
  for (int c4 = 0; c4 < 20; c4++) {
    float4 v = yr4[c4];
    y[c4 * 4] = v.x; y[c4 * 4 + 1] = v.y;
    y[c4 * 4 + 2] = v.z; y[c4 * 4 + 3] = v.w;
  }

  float out[DD];
  #pragma unroll
  for (int c = 0; c < DD; c++) out[c] = 0.0f;

  // this wave's hidden units: [80q, 80q+80) in chunks of 8
  for (int hc = 0; hc < 10; hc++) {
    float hh[8];
    {
      float4 ba = ((const float4*)b1)[q * 20 + hc * 2];
      float4 bb = ((const float4*)b1)[q * 20 + hc * 2 + 1];
      hh[0] = ba.x; hh[1] = ba.y; hh[2] = ba.z; hh[3] = ba.w;
      hh[4] = bb.x; hh[5] = bb.y; hh[6] = bb.z; hh[7] = bb.w;
    }
    #pragma unroll 20
    for (int k = 0; k < DD; k++) {
      float yv = y[k];
      float4 wa = w14[k * 40 + q * 20 + hc * 2];
      float4 wb = w14[k * 40 + q * 20 + hc * 2 + 1];
      hh[0] += yv * wa.x; hh[1] += yv * wa.y;
      hh[2] += yv * wa.z; hh[3] += yv * wa.w;
      hh[4] += yv * wb.x; hh[5] += yv * wb.y;
      hh[6] += yv * wb.z; hh[7] += yv * wb.w;
    }
    #pragma unroll
    for (int j = 0; j < 8; j++) hh[j] = gelu_f(hh[j]);
    #pragma unroll
    for (int j = 0; j < 8; j++) {
      float hv = hh[j];
      #pragma unroll
      for (int c4 = 0; c4 < 20; c4++) {
        float4 wv = w24[(q * 80 + hc * 8 + j) * 20 + c4];
        ACC4(out, c4 * 4, hv, wv)
      }
    }
  }

  // combine pair partials: column-major LDS (lane-contiguous, conflict-free)
  __shared__ float xch[DD][128];
  int tk = pr * 64 + lane;
  if (q == 0) {
    #pragma unroll
    for (int c = 0; c < DD; c++) xch[c][tk] = out[c];
  }
  __syncthreads();
  if (q == 1) {
    float s1 = 0.0f, s2 = 0.0f;
    #pragma unroll
    for (int c4 = 0; c4 < 20; c4++) {
      float4 bb = ((const float4*)b2)[c4];
      float v0 = out[c4 * 4]     + xch[c4 * 4][tk]     + bb.x + y[c4 * 4];
      float v1 = out[c4 * 4 + 1] + xch[c4 * 4 + 1][tk] + bb.y + y[c4 * 4 + 1];
      float v2 = out[c4 * 4 + 2] + xch[c4 * 4 + 2][tk] + bb.z + y[c4 * 4 + 2];
      float v3 = out[c4 * 4 + 3] + xch[c4 * 4 + 3][tk] + bb.w + y[c4 * 4 + 3];
      out[c4 * 4] = v0; out[c4 * 4 + 1] = v1;
      out[c4 * 4 + 2] = v2; out[c4 * 4 + 3] = v3;
      s1 += v0 + v1 + v2 + v3;
      s2 += v0 * v0 + v1 * v1 + v2 * v2 + v3 * v3;
    }
    float m = s1 * 0.0125f;
    float var = fmaxf(s2 * 0.0125f - m * m, 0.0f);
    float r = rsqrtf(var + 1e-5f);
    float4* xo4 = (float4*)(x + (size_t)g * DD);
    #pragma unroll
    for (int c4 = 0; c4 < 20; c4++) {
      float4 gv = ((const float4*)g2)[c4];
      float4 bv = ((const float4*)be2)[c4];
      float4 ov;
      ov.x = (out[c4 * 4]     - m) * r * gv.x + bv.x;
      ov.y = (out[c4 * 4 + 1] - m) * r * gv.y + bv.y;
      ov.z = (out[c4 * 4 + 2] - m) * r * gv.z + bv.z;
      ov.w = (out[c4 * 4 + 3] - m) * r * gv.w + bv.w;
      xo4[c4] = ov;
    }
  }
}

// ---------------------------------------------------------------------------
// K5: final LN at gathered position + fnorm + h1 = gelu(final@pr_w1+pr_b1)
// ---------------------------------------------------------------------------
__global__ __launch_bounds__(128) void k_final(
    const float* __restrict__ x, const int* __restrict__ seq_len,
    const float* __restrict__ fn_g, const float* __restrict__ fn_b,
    const float* __restrict__ pr_w1, const float* __restrict__ pr_b1,
    float* __restrict__ fnorm, float* __restrict__ h1) {
  int b = blockIdx.x, tid = threadIdx.x;
  __shared__ float red[128], red2[128];
  __shared__ float fbuf[DD];
  int t = seq_len[b] - 1; t = min(max(t, 0), LL - 1);
  float v = 0.0f;
  if (tid < DD) v = x[((size_t)b * LL + t) * DD + tid];
  red[tid]  = (tid < DD) ? v : 0.0f;
  red2[tid] = (tid < DD) ? v * v : 0.0f;
  __syncthreads();
  for (int s = 64; s > 0; s >>= 1) {
    if (tid < s) { red[tid] += red[tid + s]; red2[tid] += red2[tid + s]; }
    __syncthreads();
  }
  float mean = red[0] / DD;
  float var  = fmaxf(red2[0] / DD - mean * mean, 0.0f);
  float rstd = rsqrtf(var + 1e-5f);
  float f = 0.0f;
  if (tid < DD) { f = (v - mean) * rstd * fn_g[tid] + fn_b[tid]; fbuf[tid] = f; }
  __syncthreads();
  red[tid] = (tid < DD) ? f * f : 0.0f;
  __syncthreads();
  for (int s = 64; s > 0; s >>= 1) {
    if (tid < s) red[tid] += red[tid + s];
    __syncthreads();
  }
  float rn = 1.0f / fmaxf(sqrtf(red[0]), 1e-12f);
  if (tid < DD) {
    fnorm[(size_t)b * DD + tid] = f * rn;
    float gacc = pr_b1[tid];
    for (int i = 0; i < DD; i++) gacc += fbuf[i] * pr_w1[i * DD + tid];
    h1[(size_t)b * DD + tid] = gelu_f(gacc);
  }
}

// ---------------------------------------------------------------------------
// K6: normalize proto rows -> transposed pnormT[k][c]
// ---------------------------------------------------------------------------
__global__ __launch_bounds__(128) void k_pnorm(
    const float* __restrict__ protos, float* __restrict__ pnormT) {
  int c = blockIdx.x, tid = threadIdx.x;
  __shared__ float red[128];
  float v = 0.0f;
  if (tid < DD) v = protos[(size_t)c * DD + tid];
  red[tid] = (tid < DD) ? v * v : 0.0f;
  __syncthreads();
  for (int s = 64; s > 0; s >>= 1) {
    if (tid < s) red[tid] += red[tid + s];
    __syncthreads();
  }
  float rn = 1.0f / fmaxf(sqrtf(red[0]), 1e-12f);
  if (tid < DD) pnormT[(size_t)tid * NLOC + c] = v * rn;
}

// ---------------------------------------------------------------------------
// K7: logits — 4 batch rows per block
// ---------------------------------------------------------------------------
__global__ __launch_bounds__(256) void k_logits(
    const float* __restrict__ h1, const float* __restrict__ fnorm,
    const float* __restrict__ pr_w2, const float* __restrict__ pr_b2,
    const float* __restrict__ pnormT, const float* __restrict__ temp,
    float* __restrict__ out) {
  int b0 = (blockIdx.x / 5) * 4, cb = blockIdx.x % 5;
  int tid = threadIdx.x;
  int c = cb * 256 + tid;
  __shared__ float h1s[4][DD], fns[4][DD];
  for (int i = tid; i < 4 * DD; i += 256) {
    int j = i / DD, k = i % DD;
    h1s[j][k] = h1[(size_t)(b0 + j) * DD + k];
    fns[j][k] = fnorm[(size_t)(b0 + j) * DD + k];
  }
  __syncthreads();
  if (c < NLOC) {
    float a1[4] = {0, 0, 0, 0}, a2[4] = {0, 0, 0, 0};
    for (int k = 0; k < DD; k++) {
      float w = pr_w2[(size_t)k * NLOC + c];
      float p = pnormT[(size_t)k * NLOC + c];
      #pragma unroll
      for (int j = 0; j < 4; j++) {
        a1[j] += h1s[j][k] * w;
        a2[j] += fns[j][k] * p;
      }
    }
    float pb = pr_b2[c];
    float tt = fminf(fmaxf(temp[0], 0.5f), 3.0f);
    #pragma unroll
    for (int j = 0; j < 4; j++)
      out[(size_t)(b0 + j) * NLOC + c] = (0.5f * (a1[j] + pb) + 7.5f * a2[j]) / tt;
  }
}

// ---------------------------------------------------------------------------
extern "C" void kernel_launch(void* const* d_in, const int* in_sizes, int n_in,
                              void* d_out, int out_size, void* d_ws, size_t ws_size,
                              hipStream_t stream) {
  const int* loc_seq   = (const int*)d_in[0];
  const int* user_seq  = (const int*)d_in[1];
  const int* wk_seq    = (const int*)d_in[2];
  const int* sm_seq    = (const int*)d_in[3];
  const int* dur_seq   = (const int*)d_in[4];
  const int* diff_seq  = (const int*)d_in[5];
  const int* seq_len   = (const int*)d_in[6];
  const float* loc_table = (const float*)d_in[7];
  const float* user_table= (const float*)d_in[8];
  const float* wk_table  = (const float*)d_in[9];
  const float* hr_table  = (const float*)d_in[10];
  const float* in_w   = (const float*)d_in[11];
  const float* in_b   = (const float*)d_in[12];
  const float* in_g   = (const float*)d_in[13];
  const float* in_be  = (const float*)d_in[14];
  const float* pos_emb= (const float*)d_in[15];
  const float* qkv_w  = (const float*)d_in[16];
  const float* proj_w = (const float*)d_in[17];
  const float* proj_b = (const float*)d_in[18];
  const float* rel_emb= (const float*)d_in[19];
  const float* n1_g   = (const float*)d_in[20];
  const float* n1_b   = (const float*)d_in[21];
  const float* ffn_w1 = (const float*)d_in[22];
  const float* ffn_b1 = (const float*)d_in[23];
  const float* ffn_w2 = (const float*)d_in[24];
  const float* ffn_b2 = (const float*)d_in[25];
  const float* n2_g   = (const float*)d_in[26];
  const float* n2_b   = (const float*)d_in[27];
  const float* fn_g   = (const float*)d_in[28];
  const float* fn_b   = (const float*)d_in[29];
  const float* pr_w1  = (const float*)d_in[30];
  const float* pr_b1  = (const float*)d_in[31];
  const float* pr_w2  = (const float*)d_in[32];
  const float* pr_b2  = (const float*)d_in[33];
  const float* protos = (const float*)d_in[34];
  const float* temp   = (const float*)d_in[35];
  float* out = (float*)d_out;

  float* x      = (float*)d_ws;
  float* o      = x + (size_t)BB * LL * DD;
  float* qkvo   = o + (size_t)BB * LL * DD;
  float* fnorm  = qkvo + (size_t)BB * 14400;
  float* h1     = fnorm + (size_t)BB * DD;
  float* pnormT = h1 + (size_t)BB * DD;
  float* relTg  = pnormT + (size_t)DD * NLOC;   // 3600 floats
  float* y      = qkvo;   // qkvo is dead after k_attn; reuse for y

  k_rprep<<<15, 256, 0, stream>>>(rel_emb, relTg);

  k_embed<<<BB * LL / 128, 256, 0, stream>>>(
      loc_seq, user_seq, wk_seq, sm_seq, dur_seq, diff_seq, loc_table,
      user_table, wk_table, hr_table, in_w, in_b, in_g, in_be, pos_emb, x);

  for (int l = 0; l < NLNUM; l++) {
    k_qkv<<<(BB / 4) * 3, 256, 0, stream>>>(x, qkv_w + (size_t)l * 80 * 240, qkvo);
    k_attn<<<BB * HH, 256, 0, stream>>>(qkvo, loc_seq,
                                        relTg + (size_t)l * 1200, o);
    k_proj<<<BB * LL / 128, 256, 0, stream>>>(
        o, proj_w + (size_t)l * DD * DD, proj_b + (size_t)l * DD,
        n1_g + (size_t)l * DD, n1_b + (size_t)l * DD, x, y);
    k_ffn<<<BB * LL / 128, 256, 0, stream>>>(
        y, ffn_w1 + (size_t)l * DD * DFF, ffn_b1 + (size_t)l * DFF,
        ffn_w2 + (size_t)l * DFF * DD, ffn_b2 + (size_t)l * DD,
        n2_g + (size_t)l * DD, n2_b + (size_t)l * DD, x);
  }

  k_pnorm<<<NLOC, 128, 0, stream>>>(protos, pnormT);
  k_final<<<BB, 128, 0, stream>>>(x, seq_len, fn_g, fn_b, pr_w1, pr_b1, fnorm, h1);
  k_logits<<<(BB / 4) * 5, 256, 0, stream>>>(h1, fnorm, pr_w2, pr_b2, pnormT, temp, out);
}

// Round 5
// 1578.912 us; speedup vs baseline: 2.2566x; 2.2566x over previous
//
#include <hip/hip_runtime.h>
#include <hip/hip_bf16.h>
#include <math.h>

#define BB   2048
#define LL   60
#define DD   80
#define HH   8
#define HDD  10
#define NLNUM 3
#define NLOC 1187
#define DFF  160
#define IN_DIM 138
#define RELN 119
#define SCS  68   // sc row stride (floats): 68 mod 32 = 4 -> rows spread banks
#define XP   21   // padded tile row stride in float4 (84 words)
#define HP2  11   // h-chunk row stride in float4 (44 words)
#define VP   35   // vin row stride in float4 (140 words)
#define TS   65   // xsT row stride in float4 (260 words)

// Branchless gelu: erf via Abramowitz-Stegun 7.1.26 (|err| <= 1.5e-7).
__device__ __forceinline__ float gelu_f(float a) {
  float x = fabsf(a) * 0.70710678118654752f;
  float t = 1.0f / (1.0f + 0.3275911f * x);
  float y = t * (0.254829592f + t * (-0.284496736f + t * (1.421413741f +
            t * (-1.453152027f + t * 1.061405429f))));
  float e = 1.0f - y * __expf(-x * x);           // erf(|x|)
  float erf_s = copysignf(e, a);
  return 0.5f * a * (1.0f + erf_s);
}

// ---------------------------------------------------------------------------
// K0: pre-transpose rel_emb [l][p:119][d:10] -> relTg [l][d:10][p:120]
// ---------------------------------------------------------------------------
__global__ __launch_bounds__(256) void k_rprep(
    const float* __restrict__ rel_emb, float* __restrict__ relTg) {
  int idx = blockIdx.x * 256 + threadIdx.x;   // 3*10*120 = 3600
  if (idx >= 3600) return;
  int p = idx % 120;
  int d = (idx / 120) % 10;
  int l = idx / 1200;
  float v = 0.0f;
  if (p < RELN) v = rel_emb[l * RELN * HDD + p * HDD + d];
  relTg[idx] = v;
}

// ---------------------------------------------------------------------------
// K1 v6: embed+inproj+LN, 48-token GEMM block. in_w staged in two row-chunks
// (72/68 rows) -> LDS 50 KB (was 72 KB) -> 3 blocks/CU (was 2).
// ---------------------------------------------------------------------------
__global__ __launch_bounds__(256) void k_embed(
    const int* __restrict__ loc_seq, const int* __restrict__ user_seq,
    const int* __restrict__ wk_seq, const int* __restrict__ sm_seq,
    const int* __restrict__ dur_seq, const int* __restrict__ diff_seq,
    const float* __restrict__ loc_table, const float* __restrict__ user_table,
    const float* __restrict__ wk_table, const float* __restrict__ hr_table,
    const float* __restrict__ in_w, const float* __restrict__ in_b,
    const float* __restrict__ in_g, const float* __restrict__ in_be,
    const float* __restrict__ pos_emb, float* __restrict__ x) {
  int tok0 = blockIdx.x * 48, tid = threadIdx.x;
  __shared__ __align__(16) float vin[48 * VP * 4];   // 26880 B
  __shared__ __align__(16) float ws[1440 * 4];       // 23040 B (72 rows x 20 f4)
  __shared__ float mstd[96];

  float4* vin4 = (float4*)vin;
  float4* ws4  = (float4*)ws;

  // gather inputs into vin [48][35 f4]
  for (int i = tid; i < 48 * 35; i += 256) {
    int t = i / 35, s = i % 35;
    int tok = tok0 + t;
    float4 v;
    if (s < 20) {
      int loc = loc_seq[tok];
      v = *(const float4*)(loc_table + (size_t)loc * 80 + s * 4);
    } else if (s < 26) {
      int usr = user_seq[(tok / LL) * LL];
      v = *(const float4*)(user_table + usr * 24 + (s - 20) * 4);
    } else if (s < 30) {
      int wk = wk_seq[tok];
      v = *(const float4*)(wk_table + wk * 16 + (s - 26) * 4);
    } else if (s < 34) {
      int hr = sm_seq[tok] / 60; hr = min(max(hr, 0), 23);
      v = *(const float4*)(hr_table + hr * 16 + (s - 30) * 4);
    } else {
      v.x = (float)diff_seq[tok] / 10.0f;
      v.y = (float)dur_seq[tok] / 300.0f;
      v.z = 0.0f; v.w = 0.0f;
    }
    vin4[t * VP + s] = v;
  }

  int tg = tid / 20, cg = tid % 20, t0 = tg * 4;
  float acc[4][4] = {};
  for (int cc = 0; cc < 2; cc++) {
    int iq0 = cc * 18, niq = cc ? 17 : 18;
    for (int i = tid; i < niq * 80; i += 256) {
      int r = i / 20, c = i % 20;
      int grow = iq0 * 4 + r;
      float4 v = make_float4(0.0f, 0.0f, 0.0f, 0.0f);
      if (grow < IN_DIM) v = *(const float4*)(in_w + grow * 80 + c * 4);
      ws4[r * 20 + c] = v;
    }
    __syncthreads();
    if (tid < 240) {
      for (int iq = 0; iq < niq; iq++) {
        float4 xv[4], wv[4];
        #pragma unroll
        for (int dt = 0; dt < 4; dt++) xv[dt] = vin4[(t0 + dt) * VP + iq0 + iq];
        #pragma unroll
        for (int di = 0; di < 4; di++) wv[di] = ws4[(iq * 4 + di) * 20 + cg];
        #pragma unroll
        for (int dt = 0; dt < 4; dt++) {
          const float* xp = (const float*)&xv[dt];
          #pragma unroll
          for (int di = 0; di < 4; di++) {
            const float* wp = (const float*)&wv[di];
            #pragma unroll
            for (int dc = 0; dc < 4; dc++) acc[dt][dc] += xp[di] * wp[dc];
          }
        }
      }
    }
    __syncthreads();
  }
  if (tid < 240) {
    float4 bb = *(const float4*)(in_b + cg * 4);
    const float* bp = (const float*)&bb;
    #pragma unroll
    for (int dt = 0; dt < 4; dt++) {
      float4 y;
      y.x = acc[dt][0] + bp[0];
      y.y = acc[dt][1] + bp[1];
      y.z = acc[dt][2] + bp[2];
      y.w = acc[dt][3] + bp[3];
      vin4[(t0 + dt) * VP + cg] = y;
    }
  }
  __syncthreads();
  if (tid < 48) {
    float s = 0.0f, s2 = 0.0f;
    #pragma unroll
    for (int iq = 0; iq < 20; iq++) {
      float4 v = vin4[tid * VP + iq];
      s  += v.x + v.y + v.z + v.w;
      s2 += v.x * v.x + v.y * v.y + v.z * v.z + v.w * v.w;
    }
    float mean = s / 80.0f;
    float var  = fmaxf(s2 / 80.0f - mean * mean, 0.0f);
    mstd[tid] = mean; mstd[48 + tid] = rsqrtf(var + 1e-5f);
  }
  __syncthreads();
  for (int e = tid; e < 960; e += 256) {
    int t = e / 20, c4 = e % 20;
    float4 v = vin4[t * VP + c4];
    float4 gg = *(const float4*)(in_g + c4 * 4);
    float4 bb = *(const float4*)(in_be + c4 * 4);
    float4 pe = *(const float4*)(pos_emb + ((tok0 + t) % LL) * 80 + c4 * 4);
    float m = mstd[t], r = mstd[48 + t];
    float4 out;
    out.x = (v.x - m) * r * gg.x + bb.x + pe.x;
    out.y = (v.y - m) * r * gg.y + bb.y + pe.y;
    out.z = (v.z - m) * r * gg.z + bb.z + pe.z;
    out.w = (v.w - m) * r * gg.w + bb.w + pe.w;
    ((float4*)(x + (size_t)tok0 * 80))[e] = out;
  }
}

// ---------------------------------------------------------------------------
// K2a: qkv GEMM per batch row b -> qkvo[b][c][t]. (Round-0 proven version:
// t-fast tiles, transposed x staging, 60-col weight chunks, 40 KB LDS.)
// ---------------------------------------------------------------------------
__global__ __launch_bounds__(256) void k_qkv(
    const float* __restrict__ x, const float* __restrict__ qkv_w,
    float* __restrict__ qkvo) {
  int b = blockIdx.x, tid = threadIdx.x;
  __shared__ __align__(16) float xsT[20 * TS * 4];   // 20.8 KB  [iq][t]
  __shared__ __align__(16) float ws[80 * 60];        // 19.2 KB  [i][c4:15]

  const float4* xb4 = (const float4*)(x + (size_t)b * 4800);
  float4* xsT4 = (float4*)xsT;
  float4* ws4  = (float4*)ws;
  for (int i = tid; i < 1200; i += 256) {
    int t = i / 20, iq = i % 20;
    xsT4[iq * TS + t] = xb4[i];
  }

  for (int c0 = 0; c0 < 240; c0 += 60) {
    __syncthreads();
    for (int i = tid; i < 1200; i += 256)
      ws4[i] = *(const float4*)(qkv_w + (i / 15) * 240 + c0 + (i % 15) * 4);
    __syncthreads();
    if (tid < 225) {
      int tg = tid % 15, cg = tid / 15;
      int t0 = tg * 4;
      float acc[4][4] = {};   // [dt][dc]
      #pragma unroll 5
      for (int iq = 0; iq < 20; iq++) {
        float4 xv[4], wv[4];
        #pragma unroll
        for (int dt = 0; dt < 4; dt++) xv[dt] = xsT4[iq * TS + t0 + dt];
        #pragma unroll
        for (int di = 0; di < 4; di++) wv[di] = ws4[(iq * 4 + di) * 15 + cg];
        #pragma unroll
        for (int dt = 0; dt < 4; dt++) {
          const float* xp = (const float*)&xv[dt];
          #pragma unroll
          for (int di = 0; di < 4; di++) {
            const float* wp = (const float*)&wv[di];
            #pragma unroll
            for (int dc = 0; dc < 4; dc++) acc[dt][dc] += xp[di] * wp[dc];
          }
        }
      }
      float* qb = qkvo + (size_t)b * 14400 + (size_t)(c0 + cg * 4) * 60 + t0;
      #pragma unroll
      for (int dc = 0; dc < 4; dc++)
        *(float4*)(qb + dc * 60) =
            make_float4(acc[0][dc], acc[1][dc], acc[2][dc], acc[3][dc]);
    }
  }
}

// ---------------------------------------------------------------------------
// K2b: attention per (b,h), 256 threads; relT staged via coalesced relTg.
// ---------------------------------------------------------------------------
__global__ __launch_bounds__(256) void k_attn(
    const float* __restrict__ qkvo, const int* __restrict__ loc_seq,
    const float* __restrict__ relTg,   // layer slice [10][120]
    float* __restrict__ o) {
  int bh = blockIdx.x;
  int b = bh >> 3, h = bh & 7;
  int tid = threadIdx.x;

  __shared__ __align__(16) float qs[HDD * 60];
  __shared__ __align__(16) float ks[HDD * 60];
  __shared__ __align__(16) float vs[HDD * 60];
  __shared__ __align__(16) float relT[HDD * 120];
  __shared__ __align__(16) float sc[60 * SCS];
  __shared__ __align__(16) float rsum[64];
  __shared__ float msk[60];

  const float4* src = (const float4*)(qkvo + (size_t)b * 14400);
  float4* q4 = (float4*)qs; float4* k4 = (float4*)ks; float4* v4 = (float4*)vs;
  for (int i = tid; i < 150; i += 256) {
    q4[i] = src[h * 150 + i];
    k4[i] = src[1200 + h * 150 + i];
    v4[i] = src[2400 + h * 150 + i];
  }
  const float4* rg4 = (const float4*)relTg;
  float4* relT4 = (float4*)relT;
  for (int i = tid; i < 300; i += 256) relT4[i] = rg4[i];
  if (tid < 60) msk[tid] = (loc_seq[b * LL + tid] == 0) ? 1.0f : 0.0f;
  __syncthreads();

  if (tid < 225) {
    int ig = tid / 15, jg = tid % 15;
    int i0 = ig * 4, j0 = jg * 4;
    int w0 = j0 - i0 + 56;
    float acc[4][4] = {};
    #pragma unroll
    for (int d = 0; d < 10; d++) {
      float4 qv = *(const float4*)(qs + d * 60 + i0);
      float4 kv = *(const float4*)(ks + d * 60 + j0);
      float4 rA = *(const float4*)(relT + d * 120 + w0);
      float4 rB = *(const float4*)(relT + d * 120 + w0 + 4);
      float rr[8] = {rA.x, rA.y, rA.z, rA.w, rB.x, rB.y, rB.z, rB.w};
      const float* qp = (const float*)&qv;
      const float* kp = (const float*)&kv;
      #pragma unroll
      for (int di = 0; di < 4; di++)
        #pragma unroll
        for (int dj = 0; dj < 4; dj++)
          acc[di][dj] += qp[di] * (kp[dj] + rr[dj - di + 3]);
    }
    const float scale = 0.31622776601683794f;
    #pragma unroll
    for (int di = 0; di < 4; di++) {
      #pragma unroll
      for (int dj = 0; dj < 4; dj++) {
        float v = acc[di][dj] * scale;
        if (msk[j0 + dj] != 0.0f) v = -1e30f;
        acc[di][dj] = v;
      }
      *(float4*)(sc + (i0 + di) * SCS + j0) =
          make_float4(acc[di][0], acc[di][1], acc[di][2], acc[di][3]);
    }
  }
  __syncthreads();

  if (tid < 60) {
    float* row = sc + tid * SCS;
    int c = (tid >> 3) & 7;
    float m0 = -3.0e38f, m1 = -3.0e38f, m2 = -3.0e38f, m3 = -3.0e38f;
    #pragma unroll
    for (int s = 0; s < 15; s++) {
      int k = c + s; if (k >= 15) k -= 15;
      float4 v = *(const float4*)(row + 4 * k);
      m0 = fmaxf(m0, v.x); m1 = fmaxf(m1, v.y);
      m2 = fmaxf(m2, v.z); m3 = fmaxf(m3, v.w);
    }
    float m = fmaxf(fmaxf(m0, m1), fmaxf(m2, m3));
    float s0 = 0.0f, s1 = 0.0f, s2 = 0.0f, s3 = 0.0f;
    #pragma unroll
    for (int s = 0; s < 15; s++) {
      int k = c + s; if (k >= 15) k -= 15;
      float4 v = *(float4*)(row + 4 * k);
      v.x = __expf(v.x - m); v.y = __expf(v.y - m);
      v.z = __expf(v.z - m); v.w = __expf(v.w - m);
      *(float4*)(row + 4 * k) = v;
      s0 += v.x; s1 += v.y; s2 += v.z; s3 += v.w;
    }
    rsum[tid] = 1.0f / (s0 + s1 + s2 + s3);
  }
  __syncthreads();

  if (tid < 150) {
    int ig = tid / 10, d = tid % 10;
    float acc[4] = {0, 0, 0, 0};
    #pragma unroll 5
    for (int jq = 0; jq < 15; jq++) {
      float4 vv = *(const float4*)(vs + d * 60 + jq * 4);
      #pragma unroll
      for (int di = 0; di < 4; di++) {
        float4 av = *(const float4*)(sc + (ig + 15 * di) * SCS + jq * 4);
        acc[di] += av.x * vv.x + av.y * vv.y + av.z * vv.z + av.w * vv.w;
      }
    }
    #pragma unroll
    for (int di = 0; di < 4; di++) {
      float r = rsum[ig + 15 * di];
      o[((size_t)b * 60 + ig + 15 * di) * 80 + h * 10 + d] = acc[di] * r;
    }
  }
}

// ---------------------------------------------------------------------------
// K3 v6: fused proj+LN1+FFN+LN2, 48 tokens/block. LDS cut to 45.4 KB
// (3 blocks/CU, was 2): single 12.8 KB weight-staging buffer (chunked
// 40-col pieces), oh buffer reused as {o-tile, h-chunk, pre-LN2}; FFN B/C
// fused per 40-hidden chunk with persistent out accumulator.
// ---------------------------------------------------------------------------
__global__ __launch_bounds__(256) void k_pffn(
    const float* __restrict__ o, const float* __restrict__ proj_w,
    const float* __restrict__ proj_b, const float* __restrict__ g1,
    const float* __restrict__ be1,
    const float* __restrict__ w1, const float* __restrict__ b1,
    const float* __restrict__ w2, const float* __restrict__ b2,
    const float* __restrict__ g2, const float* __restrict__ be2,
    float* __restrict__ x) {
  int tok0 = blockIdx.x * 48, tid = threadIdx.x;
  __shared__ __align__(16) float ys[48 * XP * 4];   // 16128 B  y (post-LN1)
  __shared__ __align__(16) float oh[48 * XP * 4];   // 16128 B  o / h / pre-LN2
  __shared__ __align__(16) float ws[800 * 4];       // 12800 B  weight chunk
  __shared__ float mstd[96];

  float4* ys4 = (float4*)ys;
  float4* oh4 = (float4*)oh;
  float4* ws4 = (float4*)ws;
  const float4* pw4 = (const float4*)proj_w;  // [80][20 f4]
  const float4* w14 = (const float4*)w1;      // [80][40 f4]
  const float4* w24 = (const float4*)w2;      // [160][20 f4]

  int tgA = tid / 10, cgA = tid % 10, t0A = tgA * 2;   // 24x10 map (tid<240)
  int tgC = tid / 20, cgC = tid % 20, t0C = tgC * 4;   // 12x20 map (tid<240)

  // --- Phase A: y = LN1(x + o @ proj_w + proj_b), two 40-col chunks ---
  const float4* ob4 = (const float4*)(o + (size_t)tok0 * 80);
  for (int i = tid; i < 960; i += 256) oh4[(i / 20) * XP + (i % 20)] = ob4[i];
  for (int cc = 0; cc < 2; cc++) {
    for (int i = tid; i < 800; i += 256)
      ws4[i] = pw4[(i / 10) * 20 + cc * 10 + (i % 10)];
    __syncthreads();
    if (tid < 240) {
      float acc[2][4] = {};
      #pragma unroll 5
      for (int iq = 0; iq < 20; iq++) {
        float4 xv[2], wv[4];
        #pragma unroll
        for (int dt = 0; dt < 2; dt++) xv[dt] = oh4[(t0A + dt) * XP + iq];
        #pragma unroll
        for (int di = 0; di < 4; di++) wv[di] = ws4[(iq * 4 + di) * 10 + cgA];
        #pragma unroll
        for (int dt = 0; dt < 2; dt++) {
          const float* xp = (const float*)&xv[dt];
          #pragma unroll
          for (int di = 0; di < 4; di++) {
            const float* wp = (const float*)&wv[di];
            #pragma unroll
            for (int dc = 0; dc < 4; dc++) acc[dt][dc] += xp[di] * wp[dc];
          }
        }
      }
      float4 pb = ((const float4*)proj_b)[cc * 10 + cgA];
      const float* pbp = (const float*)&pb;
      #pragma unroll
      for (int dt = 0; dt < 2; dt++) {
        float4 xr = *(const float4*)(x + (size_t)(tok0 + t0A + dt) * 80 +
                                     (cc * 10 + cgA) * 4);
        const float* xrp = (const float*)&xr;
        float4 out;
        out.x = acc[dt][0] + pbp[0] + xrp[0];
        out.y = acc[dt][1] + pbp[1] + xrp[1];
        out.z = acc[dt][2] + pbp[2] + xrp[2];
        out.w = acc[dt][3] + pbp[3] + xrp[3];
        ys4[(t0A + dt) * XP + cc * 10 + cgA] = out;
      }
    }
    __syncthreads();
  }
  if (tid < 48) {
    float s = 0.0f, s2 = 0.0f;
    #pragma unroll
    for (int iq = 0; iq < 20; iq++) {
      float4 v = ys4[tid * XP + iq];
      s  += v.x + v.y + v.z + v.w;
      s2 += v.x * v.x + v.y * v.y + v.z * v.z + v.w * v.w;
    }
    float mean = s / 80.0f;
    float var  = fmaxf(s2 / 80.0f - mean * mean, 0.0f);
    mstd[tid] = mean; mstd[48 + tid] = rsqrtf(var + 1e-5f);
  }
  __syncthreads();
  for (int e = tid; e < 960; e += 256) {
    int t = e / 20, c4 = e % 20;
    float4 v = ys4[t * XP + c4];
    float4 gg = *(const float4*)(g1 + c4 * 4);
    float4 bb = *(const float4*)(be1 + c4 * 4);
    float m = mstd[t], r = mstd[48 + t];
    v.x = (v.x - m) * r * gg.x + bb.x;
    v.y = (v.y - m) * r * gg.y + bb.y;
    v.z = (v.z - m) * r * gg.z + bb.z;
    v.w = (v.w - m) * r * gg.w + bb.w;
    ys4[t * XP + c4] = v;
  }

  // --- Phases B+C fused per 40-hidden chunk ---
  float accC[4][4] = {};
  for (int hc = 0; hc < 4; hc++) {
    // stage w1 chunk [80 rows][40 cols]
    for (int i = tid; i < 800; i += 256)
      ws4[i] = w14[(i / 10) * 40 + hc * 10 + (i % 10)];
    __syncthreads();   // also fences ys normalize (hc=0) / prev C-GEMM reads
    if (tid < 240) {
      float acc[2][4] = {};
      #pragma unroll 5
      for (int iq = 0; iq < 20; iq++) {
        float4 xv[2], wv[4];
        #pragma unroll
        for (int dt = 0; dt < 2; dt++) xv[dt] = ys4[(t0A + dt) * XP + iq];
        #pragma unroll
        for (int di = 0; di < 4; di++) wv[di] = ws4[(iq * 4 + di) * 10 + cgA];
        #pragma unroll
        for (int dt = 0; dt < 2; dt++) {
          const float* xp = (const float*)&xv[dt];
          #pragma unroll
          for (int di = 0; di < 4; di++) {
            const float* wp = (const float*)&wv[di];
            #pragma unroll
            for (int dc = 0; dc < 4; dc++) acc[dt][dc] += xp[di] * wp[dc];
          }
        }
      }
      float4 bb = ((const float4*)b1)[hc * 10 + cgA];
      const float* bp = (const float*)&bb;
      #pragma unroll
      for (int dt = 0; dt < 2; dt++) {
        float4 hv;
        hv.x = gelu_f(acc[dt][0] + bp[0]);
        hv.y = gelu_f(acc[dt][1] + bp[1]);
        hv.z = gelu_f(acc[dt][2] + bp[2]);
        hv.w = gelu_f(acc[dt][3] + bp[3]);
        oh4[(t0A + dt) * HP2 + cgA] = hv;
      }
    }
    __syncthreads();
    // stage w2 chunk [40 rows][80 cols]
    for (int i = tid; i < 800; i += 256)
      ws4[i] = w24[(hc * 40 + i / 20) * 20 + (i % 20)];
    __syncthreads();
    if (tid < 240) {
      #pragma unroll 5
      for (int iq = 0; iq < 10; iq++) {
        float4 hv[4], wv[4];
        #pragma unroll
        for (int dt = 0; dt < 4; dt++) hv[dt] = oh4[(t0C + dt) * HP2 + iq];
        #pragma unroll
        for (int di = 0; di < 4; di++) wv[di] = ws4[(iq * 4 + di) * 20 + cgC];
        #pragma unroll
        for (int dt = 0; dt < 4; dt++) {
          const float* hp = (const float*)&hv[dt];
          #pragma unroll
          for (int di = 0; di < 4; di++) {
            const float* wp = (const float*)&wv[di];
            #pragma unroll
            for (int dc = 0; dc < 4; dc++) accC[dt][dc] += hp[di] * wp[dc];
          }
        }
      }
    }
    __syncthreads();
  }

  // --- LN2(y + f + b2) -> x ---
  if (tid < 240) {
    float4 bb = ((const float4*)b2)[cgC];
    const float* bp = (const float*)&bb;
    #pragma unroll
    for (int dt = 0; dt < 4; dt++) {
      float4 yv = ys4[(t0C + dt) * XP + cgC];   // residual = normalized y
      const float* yp = (const float*)&yv;
      float4 out;
      out.x = accC[dt][0] + bp[0] + yp[0];
      out.y = accC[dt][1] + bp[1] + yp[1];
      out.z = accC[dt][2] + bp[2] + yp[2];
      out.w = accC[dt][3] + bp[3] + yp[3];
      oh4[(t0C + dt) * XP + cgC] = out;
    }
  }
  __syncthreads();
  if (tid < 48) {
    float s = 0.0f, s2 = 0.0f;
    #pragma unroll
    for (int iq = 0; iq < 20; iq++) {
      float4 v = oh4[tid * XP + iq];
      s  += v.x + v.y + v.z + v.w;
      s2 += v.x * v.x + v.y * v.y + v.z * v.z + v.w * v.w;
    }
    float mean = s / 80.0f;
    float var  = fmaxf(s2 / 80.0f - mean * mean, 0.0f);
    mstd[tid] = mean; mstd[48 + tid] = rsqrtf(var + 1e-5f);
  }
  __syncthreads();
  for (int e = tid; e < 960; e += 256) {
    int t = e / 20, c4 = e % 20;
    float4 v = oh4[t * XP + c4];
    float4 gg = *(const float4*)(g2 + c4 * 4);
    float4 bb = *(const float4*)(be2 + c4 * 4);
    float m = mstd[t], r = mstd[48 + t];
    float4 out;
    out.x = (v.x - m) * r * gg.x + bb.x;
    out.y = (v.y - m) * r * gg.y + bb.y;
    out.z = (v.z - m) * r * gg.z + bb.z;
    out.w = (v.w - m) * r * gg.w + bb.w;
    ((float4*)(x + (size_t)tok0 * 80))[e] = out;
  }
}

// ---------------------------------------------------------------------------
// K5: final LN at gathered position + fnorm + h1 = gelu(final@pr_w1+pr_b1)
// ---------------------------------------------------------------------------
__global__ __launch_bounds__(128) void k_final(
    const float* __restrict__ x, const int* __restrict__ seq_len,
    const float* __restrict__ fn_g, const float* __restrict__ fn_b,
    const float* __restrict__ pr_w1, const float* __restrict__ pr_b1,
    float* __restrict__ fnorm, float* __restrict__ h1) {
  int b = blockIdx.x, tid = threadIdx.x;
  __shared__ float red[128], red2[128];
  __shared__ float fbuf[DD];
  int t = seq_len[b] - 1; t = min(max(t, 0), LL - 1);
  float v = 0.0f;
  if (tid < DD) v = x[((size_t)b * LL + t) * DD + tid];
  red[tid]  = (tid < DD) ? v : 0.0f;
  red2[tid] = (tid < DD) ? v * v : 0.0f;
  __syncthreads();
  for (int s = 64; s > 0; s >>= 1) {
    if (tid < s) { red[tid] += red[tid + s]; red2[tid] += red2[tid + s]; }
    __syncthreads();
  }
  float mean = red[0] / DD;
  float var  = fmaxf(red2[0] / DD - mean * mean, 0.0f);
  float rstd = rsqrtf(var + 1e-5f);
  float f = 0.0f;
  if (tid < DD) { f = (v - mean) * rstd * fn_g[tid] + fn_b[tid]; fbuf[tid] = f; }
  __syncthreads();
  red[tid] = (tid < DD) ? f * f : 0.0f;
  __syncthreads();
  for (int s = 64; s > 0; s >>= 1) {
    if (tid < s) red[tid] += red[tid + s];
    __syncthreads();
  }
  float rn = 1.0f / fmaxf(sqrtf(red[0]), 1e-12f);
  if (tid < DD) {
    fnorm[(size_t)b * DD + tid] = f * rn;
    float gacc = pr_b1[tid];
    for (int i = 0; i < DD; i++) gacc += fbuf[i] * pr_w1[i * DD + tid];
    h1[(size_t)b * DD + tid] = gelu_f(gacc);
  }
}

// ---------------------------------------------------------------------------
// K6: normalize proto rows -> transposed pnormT[k][c]
// ---------------------------------------------------------------------------
__global__ __launch_bounds__(128) void k_pnorm(
    const float* __restrict__ protos, float* __restrict__ pnormT) {
  int c = blockIdx.x, tid = threadIdx.x;
  __shared__ float red[128];
  float v = 0.0f;
  if (tid < DD) v = protos[(size_t)c * DD + tid];
  red[tid] = (tid < DD) ? v * v : 0.0f;
  __syncthreads();
  for (int s = 64; s > 0; s >>= 1) {
    if (tid < s) red[tid] += red[tid + s];
    __syncthreads();
  }
  float rn = 1.0f / fmaxf(sqrtf(red[0]), 1e-12f);
  if (tid < DD) pnormT[(size_t)tid * NLOC + c] = v * rn;
}

// ---------------------------------------------------------------------------
// K7: logits — 4 batch rows per block
// ---------------------------------------------------------------------------
__global__ __launch_bounds__(256) void k_logits(
    const float* __restrict__ h1, const float* __restrict__ fnorm,
    const float* __restrict__ pr_w2, const float* __restrict__ pr_b2,
    const float* __restrict__ pnormT, const float* __restrict__ temp,
    float* __restrict__ out) {
  int b0 = (blockIdx.x / 5) * 4, cb = blockIdx.x % 5;
  int tid = threadIdx.x;
  int c = cb * 256 + tid;
  __shared__ float h1s[4][DD], fns[4][DD];
  for (int i = tid; i < 4 * DD; i += 256) {
    int j = i / DD, k = i % DD;
    h1s[j][k] = h1[(size_t)(b0 + j) * DD + k];
    fns[j][k] = fnorm[(size_t)(b0 + j) * DD + k];
  }
  __syncthreads();
  if (c < NLOC) {
    float a1[4] = {0, 0, 0, 0}, a2[4] = {0, 0, 0, 0};
    for (int k = 0; k < DD; k++) {
      float w = pr_w2[(size_t)k * NLOC + c];
      float p = pnormT[(size_t)k * NLOC + c];
      #pragma unroll
      for (int j = 0; j < 4; j++) {
        a1[j] += h1s[j][k] * w;
        a2[j] += fns[j][k] * p;
      }
    }
    float pb = pr_b2[c];
    float tt = fminf(fmaxf(temp[0], 0.5f), 3.0f);
    #pragma unroll
    for (int j = 0; j < 4; j++)
      out[(size_t)(b0 + j) * NLOC + c] = (0.5f * (a1[j] + pb) + 7.5f * a2[j]) / tt;
  }
}

// ---------------------------------------------------------------------------
extern "C" void kernel_launch(void* const* d_in, const int* in_sizes, int n_in,
                              void* d_out, int out_size, void* d_ws, size_t ws_size,
                              hipStream_t stream) {
  const int* loc_seq   = (const int*)d_in[0];
  const int* user_seq  = (const int*)d_in[1];
  const int* wk_seq    = (const int*)d_in[2];
  const int* sm_seq    = (const int*)d_in[3];
  const int* dur_seq   = (const int*)d_in[4];
  const int* diff_seq  = (const int*)d_in[5];
  const int* seq_len   = (const int*)d_in[6];
  const float* loc_table = (const float*)d_in[7];
  const float* user_table= (const float*)d_in[8];
  const float* wk_table  = (const float*)d_in[9];
  const float* hr_table  = (const float*)d_in[10];
  const float* in_w   = (const float*)d_in[11];
  const float* in_b   = (const float*)d_in[12];
  const float* in_g   = (const float*)d_in[13];
  const float* in_be  = (const float*)d_in[14];
  const float* pos_emb= (const float*)d_in[15];
  const float* qkv_w  = (const float*)d_in[16];
  const float* proj_w = (const float*)d_in[17];
  const float* proj_b = (const float*)d_in[18];
  const float* rel_emb= (const float*)d_in[19];
  const float* n1_g   = (const float*)d_in[20];
  const float* n1_b   = (const float*)d_in[21];
  const float* ffn_w1 = (const float*)d_in[22];
  const float* ffn_b1 = (const float*)d_in[23];
  const float* ffn_w2 = (const float*)d_in[24];
  const float* ffn_b2 = (const float*)d_in[25];
  const float* n2_g   = (const float*)d_in[26];
  const float* n2_b   = (const float*)d_in[27];
  const float* fn_g   = (const float*)d_in[28];
  const float* fn_b   = (const float*)d_in[29];
  const float* pr_w1  = (const float*)d_in[30];
  const float* pr_b1  = (const float*)d_in[31];
  const float* pr_w2  = (const float*)d_in[32];
  const float* pr_b2  = (const float*)d_in[33];
  const float* protos = (const float*)d_in[34];
  const float* temp   = (const float*)d_in[35];
  float* out = (float*)d_out;

  float* x      = (float*)d_ws;
  float* o      = x + (size_t)BB * LL * DD;
  float* qkvo   = o + (size_t)BB * LL * DD;
  float* fnorm  = qkvo + (size_t)BB * 14400;
  float* h1     = fnorm + (size_t)BB * DD;
  float* pnormT = h1 + (size_t)BB * DD;
  float* relTg  = pnormT + (size_t)DD * NLOC;   // 3600 floats

  k_rprep<<<15, 256, 0, stream>>>(rel_emb, relTg);

  k_embed<<<BB * LL / 48, 256, 0, stream>>>(loc_seq, user_seq, wk_seq, sm_seq,
                                            dur_seq, diff_seq, loc_table,
                                            user_table, wk_table, hr_table,
                                            in_w, in_b, in_g, in_be, pos_emb, x);

  for (int l = 0; l < NLNUM; l++) {
    k_qkv<<<BB, 256, 0, stream>>>(x, qkv_w + (size_t)l * 80 * 240, qkvo);
    k_attn<<<BB * HH, 256, 0, stream>>>(qkvo, loc_seq,
                                        relTg + (size_t)l * 1200, o);
    k_pffn<<<BB * LL / 48, 256, 0, stream>>>(
        o, proj_w + (size_t)l * DD * DD, proj_b + (size_t)l * DD,
        n1_g + (size_t)l * DD, n1_b + (size_t)l * DD,
        ffn_w1 + (size_t)l * DD * DFF, ffn_b1 + (size_t)l * DFF,
        ffn_w2 + (size_t)l * DFF * DD, ffn_b2 + (size_t)l * DD,
        n2_g + (size_t)l * DD, n2_b + (size_t)l * DD, x);
  }

  k_pnorm<<<NLOC, 128, 0, stream>>>(protos, pnormT);
  k_final<<<BB, 128, 0, stream>>>(x, seq_len, fn_g, fn_b, pr_w1, pr_b1, fnorm, h1);
  k_logits<<<(BB / 4) * 5, 256, 0, stream>>>(h1, fnorm, pr_w2, pr_b2, pnormT, temp, out);
}